// Round 2
// baseline (13904.401 us; speedup 1.0000x reference)
//
#include <hip/hip_runtime.h>
#include <hip/hip_cooperative_groups.h>
#include <math.h>

namespace cg = cooperative_groups;

#define NN 4096
#define LBL 343
#define FINF 1e30f

// ---------------------------------------------------------------------------
// Kernel 1: Prim's MST (exact replication of reference semantics) + tree
// structure build (depths, child lists, Prim positions, edge weights).
// Single workgroup of 1024 threads; each thread owns 4 nodes in registers.
// ---------------------------------------------------------------------------
__global__ __launch_bounds__(1024) void mrf_build_kernel(
    const float* __restrict__ dist,
    float* __restrict__ w_edge,
    int* __restrict__ parent_g,
    int* __restrict__ childStart,
    int* __restrict__ childList,
    int* __restrict__ dbuf,
    int* __restrict__ pos_g,
    int* __restrict__ meta)
{
  __shared__ int s_parent[NN];   // 16 KB
  __shared__ int s_dep[NN];      // 16 KB
  __shared__ int s_anc[NN];      // 16 KB (later reused as child-count/cursor)
  __shared__ float s_rv[16];
  __shared__ int s_ri[16];
  __shared__ int s_nxt;
  __shared__ int s_wt[16];
  __shared__ int s_maxd;

  const int tid = threadIdx.x;

  // ---------------- Prim's MST ----------------
  // best[k] == FINF  <=>  node (tid*4+k) is in the tree.
  float best[4];
  int par[4];
  {
    const float4 r0 = *reinterpret_cast<const float4*>(dist + tid * 4);
    best[0] = r0.x; best[1] = r0.y; best[2] = r0.z; best[3] = r0.w;
  }
  par[0] = par[1] = par[2] = par[3] = 0;
  if (tid == 0) { best[0] = FINF; pos_g[0] = 0; }

  for (int i = 1; i < NN; ++i) {
    // local argmin over the 4 owned nodes (ascending scan + strict < keeps lowest index)
    float v = best[0];
    int bi = tid * 4;
    #pragma unroll
    for (int k = 1; k < 4; ++k)
      if (best[k] < v) { v = best[k]; bi = tid * 4 + k; }
    // wave argmin reduce (lane 0 covers all 64 lanes)
    #pragma unroll
    for (int sh = 32; sh >= 1; sh >>= 1) {
      float ov = __shfl_down(v, sh);
      int   oi = __shfl_down(bi, sh);
      if (ov < v || (ov == v && oi < bi)) { v = ov; bi = oi; }
    }
    if ((tid & 63) == 0) { s_rv[tid >> 6] = v; s_ri[tid >> 6] = bi; }
    __syncthreads();
    if (tid == 0) {
      float bv = s_rv[0]; int bj = s_ri[0];
      for (int wv = 1; wv < 16; ++wv) {
        float ov = s_rv[wv]; int oi = s_ri[wv];
        if (ov < bv || (ov == bv && oi < bj)) { bv = ov; bj = oi; }
      }
      s_nxt = bj;
      pos_g[bj] = i;   // Prim position of the newly added node
    }
    __syncthreads();
    const int nxt = s_nxt;
    if ((nxt >> 2) == tid) best[nxt & 3] = FINF;  // mark as in-tree
    // relax with row d[nxt][*]
    const float4 dr = *reinterpret_cast<const float4*>(dist + (size_t)nxt * NN + tid * 4);
    const float dv[4] = {dr.x, dr.y, dr.z, dr.w};
    #pragma unroll
    for (int k = 0; k < 4; ++k) {
      if (best[k] != FINF && dv[k] < best[k]) { best[k] = dv[k]; par[k] = nxt; }
    }
  }
  #pragma unroll
  for (int k = 0; k < 4; ++k) s_parent[tid * 4 + k] = par[k];
  __syncthreads();   // <<< CRITICAL: s_parent must be visible to all waves

  // ---------------- depth via pointer jumping (12 rounds covers depth<=4096) ----------------
  for (int j = tid; j < NN; j += 1024) {
    s_anc[j] = s_parent[j];
    s_dep[j] = (j == 0) ? 0 : 1;
  }
  __syncthreads();
  for (int r = 0; r < 12; ++r) {
    int na[4], nd[4];
    #pragma unroll
    for (int q = 0; q < 4; ++q) {
      const int j = tid + q * 1024;
      const int a = s_anc[j];
      nd[q] = s_dep[j] + s_dep[a];
      na[q] = s_anc[a];
    }
    __syncthreads();
    #pragma unroll
    for (int q = 0; q < 4; ++q) {
      const int j = tid + q * 1024;
      s_dep[j] = nd[q];
      s_anc[j] = na[q];
    }
    __syncthreads();
  }
  if (tid == 0) s_maxd = 0;
  __syncthreads();
  {
    int lm = 0;
    for (int j = tid; j < NN; j += 1024) lm = max(lm, s_dep[j]);
    atomicMax(&s_maxd, lm);
  }
  __syncthreads();
  if (tid == 0) meta[0] = s_maxd + 1;     // number of depth levels
  for (int j = tid; j < NN; j += 1024) dbuf[j] = s_dep[j];
  __syncthreads();

  // ---------------- child counts + exclusive scan + fill ----------------
  int* s_cnt = s_anc;  // reuse
  for (int j = tid; j < NN; j += 1024) s_cnt[j] = 0;
  __syncthreads();
  for (int j = tid; j < NN; j += 1024)
    if (j != 0) atomicAdd(&s_cnt[s_parent[j]], 1);
  __syncthreads();
  // block exclusive scan (blocked ownership: 4 per thread)
  const int base = tid * 4;
  const int c0 = s_cnt[base], c1 = s_cnt[base + 1], c2 = s_cnt[base + 2], c3 = s_cnt[base + 3];
  const int lsum = c0 + c1 + c2 + c3;
  const int lane = tid & 63, wid = tid >> 6;
  int incl = lsum;
  #pragma unroll
  for (int o = 1; o < 64; o <<= 1) {
    int t = __shfl_up(incl, o);
    if (lane >= o) incl += t;
  }
  if (lane == 63) s_wt[wid] = incl;
  __syncthreads();
  if (tid == 0) {
    int run = 0;
    for (int wv = 0; wv < 16; ++wv) { int t = s_wt[wv]; s_wt[wv] = run; run += t; }
  }
  __syncthreads();
  const int excl = s_wt[wid] + incl - lsum;
  s_cnt[base]     = excl;
  s_cnt[base + 1] = excl + c0;
  s_cnt[base + 2] = excl + c0 + c1;
  s_cnt[base + 3] = excl + c0 + c1 + c2;
  childStart[base]     = excl;
  childStart[base + 1] = excl + c0;
  childStart[base + 2] = excl + c0 + c1;
  childStart[base + 3] = excl + c0 + c1 + c2;
  if (tid == 1023) childStart[NN] = excl + lsum;   // == NN-1
  __syncthreads();
  // fill (unordered within a parent; consumer sorts by Prim position)
  for (int j = tid; j < NN; j += 1024)
    if (j != 0) {
      const int slot = atomicAdd(&s_cnt[s_parent[j]], 1);
      childList[slot] = j;
    }

  // ---------------- outputs: parent, edge weight ----------------
  for (int j = tid; j < NN; j += 1024) {
    parent_g[j] = s_parent[j];
    if (j == 0) {
      w_edge[0] = 0.0f;
    } else {
      const float dcp = dist[(size_t)j * NN + s_parent[j]];
      w_edge[j] = expf(-dcp / 0.18f);   // matches exp(-dist / (2*SP^2)) in f32
    }
  }
}

// ---------------------------------------------------------------------------
// Kernel 2 (cooperative): upward Viterbi messages by decreasing depth level,
// root argmax, then downward backtracking by block 0 alone.
// msgbuf aliases d_out (fully overwritten by mrf_out_kernel afterwards).
// ---------------------------------------------------------------------------
__global__ __launch_bounds__(384) void mrf_solve_kernel(
    const float* __restrict__ unary,
    const float* __restrict__ A,
    float* __restrict__ msgbuf,
    unsigned short* __restrict__ ptrbuf,
    const int* __restrict__ parent,
    const int* __restrict__ childStart,
    const int* __restrict__ childList,
    const int* __restrict__ dbuf,
    const int* __restrict__ pos_g,
    const float* __restrict__ w_edge,
    int* __restrict__ labels,
    const int* __restrict__ meta)
{
  cg::grid_group grid = cg::this_grid();
  __shared__ float s_b[LBL];
  __shared__ int s_child[1024];
  __shared__ int s_cpos[1024];
  __shared__ int s_lab[NN];   // 16 KB, used by block 0 in the down pass

  const int tid = threadIdx.x;
  int numLev = meta[0];
  if (numLev < 1) numLev = 1;
  if (numLev > NN) numLev = NN;

  // -------- upward pass: levels from deepest to root --------
  for (int lev = numLev - 1; lev >= 0; --lev) {
    for (int c = blockIdx.x; c < NN; c += gridDim.x) {
      if (dbuf[c] != lev) continue;
      const int cs = childStart[c];
      int deg = childStart[c + 1] - cs;
      if (deg < 0) deg = 0;
      if (deg > 1024) deg = 1024;   // safety clamp (never hit for random data)
      // sort children by descending Prim position = reference scan add order
      if (tid == 0) {
        for (int k = 0; k < deg; ++k) {
          const int ch = childList[cs + k];
          const int cp = pos_g[ch];
          int m = k;
          while (m > 0 && s_cpos[m - 1] < cp) {
            s_cpos[m] = s_cpos[m - 1];
            s_child[m] = s_child[m - 1];
            --m;
          }
          s_cpos[m] = cp;
          s_child[m] = ch;
        }
      }
      __syncthreads();
      // belief[c] = unary[c] + sum of children messages (exact reference order)
      if (tid < LBL) {
        float b = unary[(size_t)c * LBL + tid];
        for (int k = 0; k < deg; ++k)
          b = __fadd_rn(b, msgbuf[(size_t)s_child[k] * LBL + tid]);
        s_b[tid] = b;
      }
      __syncthreads();
      if (c != 0) {
        if (tid < LBL) {
          const float w = w_edge[c];
          // scores[lc, lp=tid] = belief[lc] + w*A[lc, lp]; max/argmax over lc
          float bv = __fadd_rn(s_b[0], __fmul_rn(w, A[tid]));
          int bi = 0;
          for (int lc = 1; lc < LBL; ++lc) {
            const float s = __fadd_rn(s_b[lc], __fmul_rn(w, A[lc * LBL + tid]));
            if (s > bv) { bv = s; bi = lc; }   // strict > keeps first max index
          }
          msgbuf[(size_t)c * LBL + tid] = bv;
          ptrbuf[(size_t)c * LBL + tid] = (unsigned short)bi;
        }
      } else if (tid == 0) {
        // root: label = argmax(belief[root]), first max index
        float bv = s_b[0]; int bi = 0;
        for (int l = 1; l < LBL; ++l)
          if (s_b[l] > bv) { bv = s_b[l]; bi = l; }
        labels[0] = bi;
      }
      __syncthreads();
    }
    __threadfence();
    grid.sync();
  }

  // -------- downward pass: block 0 only, depth levels ascending --------
  if (blockIdx.x != 0) return;
  if (tid == 0) s_lab[0] = labels[0];
  __syncthreads();
  for (int lev = 1; lev < numLev; ++lev) {
    for (int c = tid; c < NN; c += 384) {
      if (dbuf[c] == lev) {
        int pl = s_lab[parent[c] & (NN - 1)];
        if (pl < 0) pl = 0;
        if (pl >= LBL) pl = LBL - 1;      // defensive: fault-proof indexing
        const int lab = (int)ptrbuf[(size_t)c * LBL + pl];
        s_lab[c] = lab;
        labels[c] = lab;
      }
    }
    __syncthreads();
  }
}

// ---------------------------------------------------------------------------
// Kernel 3: output fill (2*onehot - 1) * 1e5  (overwrites all of d_out)
// ---------------------------------------------------------------------------
__global__ void mrf_out_kernel(const int* __restrict__ labels, float* __restrict__ out)
{
  const int id = blockIdx.x * blockDim.x + threadIdx.x;
  if (id >= NN * LBL) return;
  const int c = id / LBL;
  const int l = id - c * LBL;
  out[id] = (l == labels[c]) ? 100000.0f : -100000.0f;
}

extern "C" void kernel_launch(void* const* d_in, const int* in_sizes, int n_in,
                              void* d_out, int out_size, void* d_ws, size_t ws_size,
                              hipStream_t stream)
{
  (void)in_sizes; (void)n_in; (void)out_size; (void)ws_size;
  const float* unary = (const float*)d_in[0];
  const float* dist  = (const float*)d_in[1];
  const float* A     = (const float*)d_in[2];
  float* out = (float*)d_out;

  char* ws = (char*)d_ws;
  size_t off = 0;
  auto take = [&](size_t bytes) -> void* {
    void* p = (void*)(ws + off);
    off += (bytes + 255) & ~(size_t)255;
    return p;
  };
  // msgbuf lives in d_out (same size, fully overwritten by mrf_out_kernel).
  float* msgbuf = out;
  unsigned short* ptrbuf = (unsigned short*)take((size_t)NN * LBL * sizeof(unsigned short));
  float* w_edge     = (float*)take(NN * sizeof(float));
  int*   parent     = (int*)  take(NN * sizeof(int));
  int*   childStart = (int*)  take((NN + 1) * sizeof(int));
  int*   childList  = (int*)  take(NN * sizeof(int));
  int*   dbuf       = (int*)  take(NN * sizeof(int));
  int*   pos_g      = (int*)  take(NN * sizeof(int));
  int*   labels     = (int*)  take(NN * sizeof(int));
  int*   meta       = (int*)  take(16);

  hipLaunchKernelGGL(mrf_build_kernel, dim3(1), dim3(1024), 0, stream,
                     dist, w_edge, parent, childStart, childList, dbuf, pos_g, meta);

  void* args[] = {
    (void*)&unary, (void*)&A, (void*)&msgbuf, (void*)&ptrbuf,
    (void*)&parent, (void*)&childStart, (void*)&childList,
    (void*)&dbuf, (void*)&pos_g, (void*)&w_edge, (void*)&labels, (void*)&meta
  };
  hipLaunchCooperativeKernel((void*)mrf_solve_kernel, dim3(256), dim3(384), args, 0, stream);

  const int total = NN * LBL;
  hipLaunchKernelGGL(mrf_out_kernel, dim3((total + 255) / 256), dim3(256), 0, stream,
                     labels, out);
}

// Round 3
// 5982.299 us; speedup vs baseline: 2.3243x; 2.3243x over previous
//
#include <hip/hip_runtime.h>
#include <hip/hip_cooperative_groups.h>
#include <math.h>

namespace cg = cooperative_groups;
typedef unsigned long long u64;

#define NN 4096
#define LBL 343
#define U64MAX 0xFFFFFFFFFFFFFFFFull

// ---------------------------------------------------------------------------
// Kernel 1 (cooperative): Boruvka MST. Unique MST == Prim's tree (distinct
// weights a.s.). Per round: every row scanned by one wave (64 lanes x 16
// float4), per-component min outgoing edge via packed u64 atomicMin
// (wbits<<24 | u<<12 | v), hook + 2-cycle break, pointer-jump compress.
// ---------------------------------------------------------------------------
__global__ __launch_bounds__(1024) void mrf_boruvka_kernel(
    const float* __restrict__ dist,
    int* __restrict__ comp, u64* __restrict__ minE, int* __restrict__ hook,
    int* __restrict__ eu, int* __restrict__ ev, unsigned* __restrict__ ew,
    int* __restrict__ counters /* [0]=edge count, [1]=component count */)
{
  cg::grid_group grid = cg::this_grid();
  const int gtid = blockIdx.x * 1024 + threadIdx.x;
  const int gsize = gridDim.x * 1024;

  for (int i = gtid; i < NN; i += gsize) { comp[i] = i; minE[i] = U64MAX; }
  if (gtid == 0) { counters[0] = 0; counters[1] = NN; }
  __threadfence();
  grid.sync();

  for (int round = 0; round < 13; ++round) {
    if (((volatile int*)counters)[1] <= 1) break;

    // ---- phase 1: per-row min outgoing edge, reduce into component slot ----
    {
      const int i = gtid >> 6;        // one wave per row (4096 waves exactly)
      const int lane = gtid & 63;
      const int ci = comp[i];
      const float4* rowp = (const float4*)(dist + (size_t)i * NN);
      const int4* cp = (const int4*)comp;
      u64 best = U64MAX;
      #pragma unroll 4
      for (int k = 0; k < 16; ++k) {
        const int q = k * 64 + lane;
        const float4 dv = rowp[q];
        const int4 cv = cp[q];
        const int j0 = q * 4;
        if (cv.x != ci) { const u64 p = ((u64)__float_as_uint(dv.x) << 24) | ((u64)i << 12) | (u64)(j0    ); best = best < p ? best : p; }
        if (cv.y != ci) { const u64 p = ((u64)__float_as_uint(dv.y) << 24) | ((u64)i << 12) | (u64)(j0 + 1); best = best < p ? best : p; }
        if (cv.z != ci) { const u64 p = ((u64)__float_as_uint(dv.z) << 24) | ((u64)i << 12) | (u64)(j0 + 2); best = best < p ? best : p; }
        if (cv.w != ci) { const u64 p = ((u64)__float_as_uint(dv.w) << 24) | ((u64)i << 12) | (u64)(j0 + 3); best = best < p ? best : p; }
      }
      #pragma unroll
      for (int sh = 32; sh >= 1; sh >>= 1) {
        const u64 o = __shfl_down(best, sh);
        best = best < o ? best : o;
      }
      if (lane == 0 && best != U64MAX) atomicMin(&minE[ci], best);
    }
    __threadfence();
    grid.sync();

    // ---- phase 2: hooking with mutual-pair (2-cycle) break, record edges ----
    for (int i = gtid; i < NN; i += gsize) {
      int h = comp[i];
      if (h == i) {
        const u64 e = minE[i];
        if (e != U64MAX) {
          const int v = (int)(e & 0xFFF);
          const int u = (int)((e >> 12) & 0xFFF);
          const unsigned wb = (unsigned)(e >> 24);
          const int t = comp[v];
          const u64 te = minE[t];
          const int tv = (int)(te & 0xFFF);
          const bool mutual = (te != U64MAX) && (comp[tv] == i);
          if (!(mutual && i < t)) {           // mutual pair: smaller root stays
            h = t;
            const int slot = atomicAdd(&counters[0], 1);
            eu[slot] = u; ev[slot] = v; ew[slot] = wb;
          }
        }
      }
      hook[i] = h;
    }
    if (gtid == 0) counters[1] = 0;
    __threadfence();
    grid.sync();

    // ---- phase 3: compress by chasing hook[] (acyclic), count roots ----
    for (int i = gtid; i < NN; i += gsize) {
      int c = hook[i];
      int guard = 0;
      while (hook[c] != c && guard++ < NN) c = hook[c];
      comp[i] = c;
      minE[i] = U64MAX;
      if (c == i) atomicAdd(&counters[1], 1);
    }
    __threadfence();
    grid.sync();
  }
}

// ---------------------------------------------------------------------------
// block-wide exclusive scan over 4096 LDS ints (1024 threads, 4/thread)
// ---------------------------------------------------------------------------
__device__ __forceinline__ void scan4096(int* arr, int* tmp16, int tid)
{
  __syncthreads();
  const int base = tid * 4;
  const int c0 = arr[base], c1 = arr[base + 1], c2 = arr[base + 2], c3 = arr[base + 3];
  const int lsum = c0 + c1 + c2 + c3;
  const int lane = tid & 63, wid = tid >> 6;
  int incl = lsum;
  #pragma unroll
  for (int o = 1; o < 64; o <<= 1) {
    const int t = __shfl_up(incl, o);
    if (lane >= o) incl += t;
  }
  if (lane == 63) tmp16[wid] = incl;
  __syncthreads();
  if (tid == 0) {
    int run = 0;
    for (int w = 0; w < 16; ++w) { const int t = tmp16[w]; tmp16[w] = run; run += t; }
  }
  __syncthreads();
  const int excl = tmp16[wid] + incl - lsum;
  arr[base]     = excl;
  arr[base + 1] = excl + c0;
  arr[base + 2] = excl + c0 + c1;
  arr[base + 3] = excl + c0 + c1 + c2;
  __syncthreads();
}

// ---------------------------------------------------------------------------
// Kernel 2 (single block, 1024 thr): root MST at node 0.
// - CSR adjacency from edge list (entries packed (wbits<<12)|nbr as u64)
// - BFS for parent[]/depth[] (tree => race-free discovery)
// - child lists sorted DESCENDING by (wbits, idx)  == reversed Prim order
// - per-depth node buckets (levStart/levNodes) for the solve schedule
// - w_edge[c] = expf(-dist[c][parent]/0.18f)
// ---------------------------------------------------------------------------
__global__ __launch_bounds__(1024) void mrf_root_kernel(
    const float* __restrict__ dist,
    const int* __restrict__ eu, const int* __restrict__ ev, const unsigned* __restrict__ ew,
    int* __restrict__ parent_g, int* __restrict__ childStart, int* __restrict__ childList,
    int* __restrict__ levStart, int* __restrict__ levNodes,
    int* __restrict__ meta, float* __restrict__ w_edge,
    u64* __restrict__ adjList)
{
  __shared__ int s_deg[NN];                 // 16 KB
  __shared__ int s_start[NN];               // 16 KB (adj CSR start; later level cursor)
  __shared__ int s_cur[NN];                 // 16 KB (adj cursor; later level counts)
  __shared__ int s_parent[NN];              // 16 KB
  __shared__ unsigned short s_dep[NN];      // 8 KB
  __shared__ unsigned short s_fr[2][NN];    // 16 KB frontiers (reused as int* later)
  __shared__ int s_tmp16[16];
  __shared__ int s_fcnt, s_nf;

  const int tid = threadIdx.x;

  // ---- adjacency ----
  for (int j = tid; j < NN; j += 1024) s_deg[j] = 0;
  __syncthreads();
  for (int e = tid; e < NN - 1; e += 1024) {
    atomicAdd(&s_deg[eu[e] & (NN - 1)], 1);
    atomicAdd(&s_deg[ev[e] & (NN - 1)], 1);
  }
  __syncthreads();
  for (int j = tid; j < NN; j += 1024) s_start[j] = s_deg[j];
  scan4096(s_start, s_tmp16, tid);
  for (int j = tid; j < NN; j += 1024) s_cur[j] = s_start[j];
  __syncthreads();
  for (int e = tid; e < NN - 1; e += 1024) {
    const int u = eu[e] & (NN - 1), v = ev[e] & (NN - 1);
    const u64 wb = (u64)ew[e];
    const int p1 = atomicAdd(&s_cur[u], 1);
    adjList[p1] = (wb << 12) | (u64)v;
    const int p2 = atomicAdd(&s_cur[v], 1);
    adjList[p2] = (wb << 12) | (u64)u;
  }
  __syncthreads();

  // ---- BFS from node 0 ----
  for (int j = tid; j < NN; j += 1024) { s_parent[j] = 0; s_dep[j] = 0; }
  if (tid == 0) { s_fcnt = 1; s_nf = 0; s_fr[0][0] = 0; }
  __syncthreads();
  int cur = 0, lev = 0;
  while (true) {
    const int fcnt = s_fcnt;
    if (fcnt == 0) break;
    for (int idx = tid; idx < fcnt; idx += 1024) {
      const int x = s_fr[cur][idx];
      const int st = s_start[x], dg = s_deg[x];
      for (int a = 0; a < dg; ++a) {
        const u64 ent = adjList[st + a];
        const int nb = (int)(ent & 0xFFF);
        if (nb != s_parent[x] || x == 0) {     // tree: each nb discovered once
          s_parent[nb] = x;
          s_dep[nb] = (unsigned short)(lev + 1);
          const int slot = atomicAdd(&s_nf, 1);
          s_fr[1 - cur][slot] = (unsigned short)nb;
        }
      }
    }
    __syncthreads();
    if (tid == 0) { s_fcnt = s_nf; s_nf = 0; }
    ++lev;
    cur ^= 1;
    __syncthreads();
  }
  const int numLev = lev;
  if (tid == 0) { s_parent[0] = 0; meta[0] = numLev; }
  __syncthreads();

  // ---- childStart (counts = deg - 1 for non-root) ----
  int* s_cs2 = (int*)s_fr;   // frontier memory reused (16 KB = 4096 ints)
  for (int j = tid; j < NN; j += 1024) s_cs2[j] = s_deg[j] - (j != 0 ? 1 : 0);
  scan4096(s_cs2, s_tmp16, tid);
  for (int j = tid; j < NN; j += 1024) childStart[j] = s_cs2[j];
  if (tid == 0) childStart[NN] = NN - 1;
  __syncthreads();

  // ---- children sorted descending by (wbits, idx) ----
  for (int p = tid; p < NN; p += 1024) {
    const int st = s_start[p], dg = s_deg[p], cs = s_cs2[p];
    const int par = s_parent[p];
    u64 buf[16];
    int m = 0;
    for (int a = 0; a < dg; ++a) {
      const u64 ent = adjList[st + a];
      const int nb = (int)(ent & 0xFFF);
      if (p != 0 && nb == par) continue;
      if (m < 16) {
        int q = m;
        while (q > 0 && buf[q - 1] < ent) { buf[q] = buf[q - 1]; --q; }
        buf[q] = ent;
        ++m;
      } else {
        childList[cs + m] = nb;  // unsorted overflow (deg>16: ~impossible)
        ++m;
      }
    }
    const int lim = m < 16 ? m : 16;
    for (int k = 0; k < lim; ++k) childList[cs + k] = (int)(buf[k] & 0xFFF);
  }

  // ---- level buckets ----
  for (int j = tid; j < NN; j += 1024) s_cur[j] = 0;
  __syncthreads();
  for (int j = tid; j < NN; j += 1024) atomicAdd(&s_cur[s_dep[j]], 1);
  scan4096(s_cur, s_tmp16, tid);
  for (int j = tid; j < NN; j += 1024) { levStart[j] = s_cur[j]; s_start[j] = s_cur[j]; }
  if (tid == 0) levStart[NN] = NN;
  __syncthreads();
  for (int j = tid; j < NN; j += 1024) {
    const int pos = atomicAdd(&s_start[s_dep[j]], 1);
    levNodes[pos] = j;
  }

  // ---- outputs ----
  for (int j = tid; j < NN; j += 1024) {
    parent_g[j] = s_parent[j];
    w_edge[j] = (j == 0) ? 0.0f
                         : expf(-dist[(size_t)j * NN + s_parent[j]] / 0.18f);
  }
}

// ---------------------------------------------------------------------------
// Kernel 3 (cooperative): upward Viterbi by decreasing depth level (per-level
// node buckets), root argmax, then block-0 downward backtracking.
// msgbuf aliases d_out (fully overwritten afterwards).
// ---------------------------------------------------------------------------
__global__ __launch_bounds__(384) void mrf_solve_kernel(
    const float* __restrict__ unary, const float* __restrict__ A,
    float* __restrict__ msgbuf, unsigned short* __restrict__ ptrbuf,
    const int* __restrict__ parent, const int* __restrict__ childStart,
    const int* __restrict__ childList, const int* __restrict__ levStart,
    const int* __restrict__ levNodes, const float* __restrict__ w_edge,
    int* __restrict__ labels, const int* __restrict__ meta)
{
  cg::grid_group grid = cg::this_grid();
  __shared__ float s_b[LBL];
  __shared__ int s_lab[NN];
  const int tid = threadIdx.x;
  int numLev = meta[0];
  if (numLev < 1) numLev = 1;
  if (numLev > NN) numLev = NN;

  // -------- upward --------
  for (int lev = numLev - 1; lev >= 0; --lev) {
    int ls = levStart[lev], le = levStart[lev + 1];
    if (ls < 0) ls = 0;
    if (le > NN) le = NN;
    for (int idx = ls + blockIdx.x; idx < le; idx += gridDim.x) {
      const int c = levNodes[idx] & (NN - 1);
      int cs = childStart[c], ce = childStart[c + 1];
      if (cs < 0) cs = 0;
      if (ce > NN - 1) ce = NN - 1;
      if (ce < cs) ce = cs;
      if (tid < LBL) {
        float b = unary[(size_t)c * LBL + tid];
        for (int k = cs; k < ce; ++k) {
          const int ch = childList[k] & (NN - 1);
          b = __fadd_rn(b, msgbuf[(size_t)ch * LBL + tid]);
        }
        s_b[tid] = b;
      }
      __syncthreads();
      if (c != 0) {
        if (tid < LBL) {
          const float w = w_edge[c];
          float bv = __fadd_rn(s_b[0], __fmul_rn(w, A[tid]));
          int bi = 0;
          for (int lc = 1; lc < LBL; ++lc) {
            const float s = __fadd_rn(s_b[lc], __fmul_rn(w, A[lc * LBL + tid]));
            if (s > bv) { bv = s; bi = lc; }   // strict > keeps first max index
          }
          msgbuf[(size_t)c * LBL + tid] = bv;
          ptrbuf[(size_t)c * LBL + tid] = (unsigned short)bi;
        }
      } else if (tid == 0) {
        float bv = s_b[0]; int bi = 0;
        for (int l = 1; l < LBL; ++l)
          if (s_b[l] > bv) { bv = s_b[l]; bi = l; }
        labels[0] = bi;
      }
      __syncthreads();
    }
    __threadfence();
    grid.sync();
  }

  // -------- downward (block 0) --------
  if (blockIdx.x != 0) return;
  if (tid == 0) s_lab[0] = labels[0];
  __syncthreads();
  for (int lev = 1; lev < numLev; ++lev) {
    int ls = levStart[lev], le = levStart[lev + 1];
    if (ls < 0) ls = 0;
    if (le > NN) le = NN;
    for (int idx = ls + tid; idx < le; idx += 384) {
      const int c = levNodes[idx] & (NN - 1);
      int pl = s_lab[parent[c] & (NN - 1)];
      if (pl < 0) pl = 0;
      if (pl >= LBL) pl = LBL - 1;
      const int lab = (int)ptrbuf[(size_t)c * LBL + pl];
      s_lab[c] = lab;
      labels[c] = lab;
    }
    __syncthreads();
  }
}

// ---------------------------------------------------------------------------
// Kernel 4: output fill (2*onehot - 1) * 1e5 (overwrites all of d_out)
// ---------------------------------------------------------------------------
__global__ void mrf_out_kernel(const int* __restrict__ labels, float* __restrict__ out)
{
  const int id = blockIdx.x * blockDim.x + threadIdx.x;
  if (id >= NN * LBL) return;
  const int c = id / LBL;
  const int l = id - c * LBL;
  out[id] = (l == labels[c]) ? 100000.0f : -100000.0f;
}

extern "C" void kernel_launch(void* const* d_in, const int* in_sizes, int n_in,
                              void* d_out, int out_size, void* d_ws, size_t ws_size,
                              hipStream_t stream)
{
  (void)in_sizes; (void)n_in; (void)out_size; (void)ws_size;
  const float* unary = (const float*)d_in[0];
  const float* dist  = (const float*)d_in[1];
  const float* A     = (const float*)d_in[2];
  float* out = (float*)d_out;

  char* ws = (char*)d_ws;
  size_t off = 0;
  auto take = [&](size_t bytes) -> void* {
    void* p = (void*)(ws + off);
    off += (bytes + 255) & ~(size_t)255;
    return p;
  };
  float* msgbuf = out;   // aliases d_out; fully overwritten by mrf_out_kernel
  unsigned short* ptrbuf = (unsigned short*)take((size_t)NN * LBL * sizeof(unsigned short));
  int*      comp       = (int*)     take(NN * sizeof(int));
  u64*      minE       = (u64*)     take(NN * sizeof(u64));
  int*      hook       = (int*)     take(NN * sizeof(int));
  int*      eu         = (int*)     take(NN * sizeof(int));
  int*      ev         = (int*)     take(NN * sizeof(int));
  unsigned* ew         = (unsigned*)take(NN * sizeof(unsigned));
  int*      counters   = (int*)     take(256);
  int*      parent     = (int*)     take(NN * sizeof(int));
  int*      childStart = (int*)     take((NN + 1) * sizeof(int));
  int*      childList  = (int*)     take(NN * sizeof(int));
  int*      levStart   = (int*)     take((NN + 1) * sizeof(int));
  int*      levNodes   = (int*)     take(NN * sizeof(int));
  int*      labels     = (int*)     take(NN * sizeof(int));
  int*      meta       = (int*)     take(256);
  float*    w_edge     = (float*)   take(NN * sizeof(float));
  u64*      adjList    = (u64*)     take((size_t)2 * NN * sizeof(u64));

  {
    void* args[] = {
      (void*)&dist, (void*)&comp, (void*)&minE, (void*)&hook,
      (void*)&eu, (void*)&ev, (void*)&ew, (void*)&counters
    };
    hipLaunchCooperativeKernel((void*)mrf_boruvka_kernel, dim3(256), dim3(1024),
                               args, 0, stream);
  }

  hipLaunchKernelGGL(mrf_root_kernel, dim3(1), dim3(1024), 0, stream,
                     dist, eu, ev, ew, parent, childStart, childList,
                     levStart, levNodes, meta, w_edge, adjList);

  {
    void* args[] = {
      (void*)&unary, (void*)&A, (void*)&msgbuf, (void*)&ptrbuf,
      (void*)&parent, (void*)&childStart, (void*)&childList,
      (void*)&levStart, (void*)&levNodes, (void*)&w_edge,
      (void*)&labels, (void*)&meta
    };
    hipLaunchCooperativeKernel((void*)mrf_solve_kernel, dim3(256), dim3(384),
                               args, 0, stream);
  }

  const int total = NN * LBL;
  hipLaunchKernelGGL(mrf_out_kernel, dim3((total + 255) / 256), dim3(256), 0, stream,
                     labels, out);
}